// Round 5
// baseline (183.346 us; speedup 1.0000x reference)
//
#include <hip/hip_runtime.h>
#include <math.h>

#define TPB 256

// R = I + a*K + b*K^2 with K=skew(v), K^2 = v v^T - th^2 I
// => R = (1 - b*th^2) I + b * v v^T + a * K   (matches reference incl. small-angle branch)
__device__ __forceinline__ void rodrigues(float v0, float v1, float v2, float R[9]) {
    float th2 = v0 * v0 + v1 * v1 + v2 * v2;
    float th  = sqrtf(th2);
    float s, c;
    sincosf(th, &s, &c);
    bool  sm = th < 1e-6f;
    float a  = sm ? 1.0f : s / th;
    float b  = sm ? 0.5f : (1.0f - c) / th2;
    float cc = 1.0f - b * th2;
    R[0] = cc + b * v0 * v0;      R[1] = b * v0 * v1 - a * v2;  R[2] = b * v0 * v2 + a * v1;
    R[3] = b * v0 * v1 + a * v2;  R[4] = cc + b * v1 * v1;      R[5] = b * v1 * v2 - a * v0;
    R[6] = b * v0 * v2 - a * v1;  R[7] = b * v1 * v2 + a * v0;  R[8] = cc + b * v2 * v2;
}

// One 256-element tile per block (round-0 grid shape, proven to stream well).
// Input: LDS-staged coalesced float4 (192 threads x 1 float4 per array).
// Output: DIRECT stores — each thread writes its 3 float4s back-to-back; a wave's
// 3 store instructions cover one contiguous 3 KB span within a few cycles, so L2
// merges partial lines (unlike R1's long-window 192B/thread comb that +50%'d WRITE).
// This deletes s_out (24->12 KB LDS: 6->8 blocks/CU residency), the second
// barrier, and the output LDS round-trip.
__global__ __launch_bounds__(TPB) void aff_kernel(
    const float4* __restrict__ trans,
    const float4* __restrict__ rotat,
    const float4* __restrict__ sdir,
    const float4* __restrict__ scal,
    float4* __restrict__ out,
    int B)
{
    __shared__ float s_in[4][TPB * 3];   // 12 KB: 768 floats per input array

    const int tid  = threadIdx.x;
    const int base = blockIdx.x * TPB;           // first element of this block
    const int n    = min(TPB, B - base);         // elements in this block (256 or tail)
    const int nf4  = (n * 3) >> 2;               // float4s per input (n*3 divisible by 4)

    // ---- coalesced global -> LDS: 192 consecutive float4 per input ----
    if (tid < nf4) {
        const int gbase = (base * 3) >> 2;       // = blockIdx.x * 192
        float4 a = trans[gbase + tid];
        float4 b = rotat[gbase + tid];
        float4 c = sdir [gbase + tid];
        float4 d = scal [gbase + tid];
        ((float4*)&s_in[0][0])[tid] = a;
        ((float4*)&s_in[1][0])[tid] = b;
        ((float4*)&s_in[2][0])[tid] = c;
        ((float4*)&s_in[3][0])[tid] = d;
    }
    __syncthreads();

    // ---- compute: one element per thread; LDS reads at stride 3 (2 lanes/bank = free) ----
    if (tid < n) {
        float t0 = s_in[0][3*tid+0], t1 = s_in[0][3*tid+1], t2 = s_in[0][3*tid+2];

        float R[9], U[9];
        rodrigues(s_in[1][3*tid+0], s_in[1][3*tid+1], s_in[1][3*tid+2], R);
        rodrigues(s_in[2][3*tid+0], s_in[2][3*tid+1], s_in[2][3*tid+2], U);
        const float d0 = expf(s_in[3][3*tid+0]);
        const float d1 = expf(s_in[3][3*tid+1]);
        const float d2 = expf(s_in[3][3*tid+2]);

        // W = U * diag(d)
        const float W0 = U[0]*d0, W1 = U[1]*d1, W2 = U[2]*d2;
        const float W3 = U[3]*d0, W4 = U[4]*d1, W5 = U[5]*d2;
        const float W6 = U[6]*d0, W7 = U[7]*d1, W8 = U[8]*d2;

        // S = W * U^T (symmetric — fp-identical to full 3x3, verified passing)
        const float S00 = W0*U[0] + W1*U[1] + W2*U[2];
        const float S01 = W0*U[3] + W1*U[4] + W2*U[5];
        const float S02 = W0*U[6] + W1*U[7] + W2*U[8];
        const float S11 = W3*U[3] + W4*U[4] + W5*U[5];
        const float S12 = W3*U[6] + W4*U[7] + W5*U[8];
        const float S22 = W6*U[6] + W7*U[7] + W8*U[8];

        // M = R * S
        const float M00 = R[0]*S00 + R[1]*S01 + R[2]*S02;
        const float M01 = R[0]*S01 + R[1]*S11 + R[2]*S12;
        const float M02 = R[0]*S02 + R[1]*S12 + R[2]*S22;
        const float M10 = R[3]*S00 + R[4]*S01 + R[5]*S02;
        const float M11 = R[3]*S01 + R[4]*S11 + R[5]*S12;
        const float M12 = R[3]*S02 + R[4]*S12 + R[5]*S22;
        const float M20 = R[6]*S00 + R[7]*S01 + R[8]*S02;
        const float M21 = R[6]*S01 + R[7]*S11 + R[8]*S12;
        const float M22 = R[6]*S02 + R[7]*S12 + R[8]*S22;

        // direct coalesced-enough stores: 3 float4 back-to-back per thread,
        // wave covers contiguous [base+...]*48B span within a few cycles
        float4* o = out + 3 * (base + tid);
        o[0] = make_float4(M00, M01, M02, t0);
        o[1] = make_float4(M10, M11, M12, t1);
        o[2] = make_float4(M20, M21, M22, t2);
    }
}

extern "C" void kernel_launch(void* const* d_in, const int* in_sizes, int n_in,
                              void* d_out, int out_size, void* d_ws, size_t ws_size,
                              hipStream_t stream) {
    int B = in_sizes[0] / 3;                     // 2,000,000 elements
    int blocks = (B + TPB - 1) / TPB;            // 7813 single-tile blocks
    aff_kernel<<<blocks, TPB, 0, stream>>>((const float4*)d_in[0], (const float4*)d_in[1],
                                           (const float4*)d_in[2], (const float4*)d_in[3],
                                           (float4*)d_out, B);
}